// Round 7
// baseline (146.511 us; speedup 1.0000x reference)
//
#include <hip/hip_runtime.h>
#include <hip/hip_bf16.h>

// ---------------------------------------------------------------------------
// TwoSimplicialAttention  (B=2, T=192, C=512, H=8, D=64)
// R11: two independent changes:
//  attn: (1) S-sum via MFMA ones-A-frag (replaces 24 scalar adds/kstep),
//        (2) K2 staged in LDS as f32 (kills 16 v_lshlrev/kstep),
//        (3) kstep body batched into stages (12 L-MFMA -> 24 exp -> 12 pack
//            -> 3 S-MFMA + 12 PV-MFMA) for ILP. VALU/kstep ~92 -> ~52 ops.
//  proj: epilogue rewritten through a padded LDS tile -- all global stores
//        now coalesced uint4 (v1t case was 1024 scattered 2B stores/block).
//        which/h/b/bh/tt0/d0 are tile-constant; single-wave block, 1 barrier.
// ---------------------------------------------------------------------------

typedef float  v4f __attribute__((ext_vector_type(4)));
typedef short  v8s __attribute__((ext_vector_type(8)));

__device__ __forceinline__ unsigned short f2bf(float f) {
  unsigned u = __float_as_uint(f);
  u += 0x7fffu + ((u >> 16) & 1u);       // RNE
  return (unsigned short)(u >> 16);
}
__device__ __forceinline__ float bf2f(unsigned short b) {
  return __uint_as_float(((unsigned)b) << 16);
}
__device__ __forceinline__ unsigned pack_bf16(float lo, float hi) {
  __hip_bfloat162 t = __float22bfloat162_rn(float2{lo, hi});
  union { __hip_bfloat162 b; unsigned u; } cv;
  cv.b = t;
  return cv.u;
}

#if __has_builtin(__builtin_amdgcn_exp2f)
#define EXP2F(x) __builtin_amdgcn_exp2f(x)
#else
#define EXP2F(x) exp2f(x)
#endif

#define MFMA32(a, b, c) __builtin_amdgcn_mfma_f32_16x16x32_bf16((a), (b), (c), 0, 0, 0)

// q scale = D^-0.5 * log2(e)
#define QSCALE 0.18033688011112042f

// ws layout, floats (wsf):
//   qs   [16][192][64]        @ 0        (q * 0.125*log2e, fp32)
//   v2p  [16][192][64]        @ 196608   (fp32, linear [k][d])
//   accp [16][12][4][16][64]  @ 393216
//   Sp   [16][12][4][16]      @ 1179648  (total fp32: 1191936)
// ws layout, ushort (wsh = wsf + 1191936):
//   k1b  [16][192][64]  @ 0
//   k2b  [16][192][64]  @ 196608
//   v1t  [16][64][192]  @ 393216   (columns PERMUTED within 32-chunks)
//   xh   [384][512]     @ 589824      xl @ 786432
//   Wth  [2560][512]    @ 983040      Wtl @ 2293760   (W_in^T, k-major)
//   Woth [512][512]     @ 3604480     Wotl @ 3866624  (W_out^T, k-major)
//   oh   [384][512]     @ 4128768     ol  @ 4325376   (normalized out)

#define XH_OFF   589824
#define XL_OFF   786432
#define WTH_OFF  983040
#define WTL_OFF  2293760
#define WOTH_OFF 3604480
#define WOTL_OFF 3866624
#define OH_OFF   4128768
#define OL_OFF   4325376

// V1 column position for j-offset t within a 32-chunk (R10 ordering):
//   quad = (t>>2)&3, hi = (t>>4)&1, r = t&3  ->  p = quad*8 + hi*4 + r
// inverse: t = ((p>>3)&3)<<2 | ((p>>2)&1)<<4 | (p&3)
__device__ __forceinline__ int v1perm_inv(int p) {
  return (((p >> 3) & 3) << 2) | (((p >> 2) & 1) << 4) | (p & 3);
}

// ------------------------------ Phase 0: prep ------------------------------
// grid 864: [0,640) W_in transpose+split (64n x 32k tiles), [640,768) W_out,
// [768,864) x hi/lo split. W goes through LDS so global writes are dense.
__global__ __launch_bounds__(256) void prep_kernel(
    const float* __restrict__ x, const float* __restrict__ Win,
    const float* __restrict__ Wout, unsigned short* __restrict__ wsh) {
  __shared__ float tile[32 * 65];
  const int bi = blockIdx.x, t = threadIdx.x;
  if (bi < 768) {
    const float* W; unsigned short *Th, *Tl; int R, n0, k0;
    if (bi < 640) {
      W = Win; Th = wsh + WTH_OFF; Tl = wsh + WTL_OFF; R = 2560;
      n0 = (bi % 40) << 6; k0 = (bi / 40) << 5;
    } else {
      const int idx = bi - 640;
      W = Wout; Th = wsh + WOTH_OFF; Tl = wsh + WOTL_OFF; R = 512;
      n0 = (idx & 7) << 6; k0 = (idx >> 3) << 5;
    }
    // phase 1: coalesced reads -> LDS [k][n] (pad 65)
    const int n = t & 63, kq = (t >> 6) * 8;
#pragma unroll
    for (int j = 0; j < 8; ++j)
      tile[(kq + j) * 65 + n] = W[(k0 + kq + j) * R + n0 + n];
    __syncthreads();
    // phase 2: k-contig hi/lo writes (dense 64B lines)
    const int n2 = t >> 2, ks = (t & 3) * 8;
    union { uint4 u; unsigned short us[8]; } ph, pl;
#pragma unroll
    for (int j = 0; j < 8; ++j) {
      const float v = tile[(ks + j) * 65 + n2];
      const unsigned short h = f2bf(v);
      ph.us[j] = h;
      pl.us[j] = f2bf(v - bf2f(h));
    }
    *(uint4*)(Th + (n0 + n2) * 512 + k0 + ks) = ph.u;
    *(uint4*)(Tl + (n0 + n2) * 512 + k0 + ks) = pl.u;
  } else {
    const int flat = ((bi - 768) * 256 + t) * 8;
    const v4f v0 = *(const v4f*)(x + flat);
    const v4f v1 = *(const v4f*)(x + flat + 4);
    union { uint4 u; unsigned short us[8]; } ph, pl;
#pragma unroll
    for (int j = 0; j < 4; ++j) {
      unsigned short h = f2bf(v0[j]);
      ph.us[j] = h; pl.us[j] = f2bf(v0[j] - bf2f(h));
      h = f2bf(v1[j]);
      ph.us[4 + j] = h; pl.us[4 + j] = f2bf(v1[j] - bf2f(h));
    }
    *(uint4*)(wsh + XH_OFF + flat) = ph.u;
    *(uint4*)(wsh + XL_OFF + flat) = pl.u;
  }
}

// ------------------------------ Phase 1: proj (bf16x3 MFMA) ----------------
// grid 960 x 64thr: 1 wave/block, 32x32 C-tile, prefetch depth 2.
// Epilogue: LDS tile -> coalesced per-which stores (tile-constant which/bh).
__global__ __launch_bounds__(64) void proj_kernel(
    const unsigned short* __restrict__ wsh, const float* __restrict__ bin,
    float* __restrict__ wsf, unsigned short* __restrict__ wshd) {
  __shared__ float tile[32 * 33];
  const int lane = threadIdx.x;
  const int c = lane & 15, q = lane >> 4;
  const int bm = blockIdx.x % 12, bn = blockIdx.x / 12;

  const unsigned short* base[8];
  base[0] = wsh + XH_OFF + (bm * 32 + c) * 512 + (q << 3);
  base[1] = base[0] + 16 * 512;
  base[2] = wsh + XL_OFF + (bm * 32 + c) * 512 + (q << 3);
  base[3] = base[2] + 16 * 512;
  base[4] = wsh + WTH_OFF + (bn * 32 + c) * 512 + (q << 3);
  base[5] = base[4] + 16 * 512;
  base[6] = wsh + WTL_OFF + (bn * 32 + c) * 512 + (q << 3);
  base[7] = base[6] + 16 * 512;

  const v4f z = {0.f, 0.f, 0.f, 0.f};
  v4f a00 = z, a01 = z, a10 = z, a11 = z;

  v8s cur[8], nxt[8];
#pragma unroll
  for (int i = 0; i < 8; ++i) cur[i] = *(const v8s*)(base[i]);
#pragma unroll
  for (int i = 0; i < 8; ++i) nxt[i] = *(const v8s*)(base[i] + 32);

#pragma unroll 1
  for (int ks = 0; ks < 16; ++ks) {
    v8s nx2[8];
    if (ks < 14) {
      const int o = (ks + 2) * 32;
#pragma unroll
      for (int i = 0; i < 8; ++i) nx2[i] = *(const v8s*)(base[i] + o);
    }
    // Ah0,Ah1,Al0,Al1 = cur[0..3]; Bh0,Bh1,Bl0,Bl1 = cur[4..7]
    a00 = MFMA32(cur[2], cur[4], a00); a00 = MFMA32(cur[0], cur[6], a00); a00 = MFMA32(cur[0], cur[4], a00);
    a01 = MFMA32(cur[2], cur[5], a01); a01 = MFMA32(cur[0], cur[7], a01); a01 = MFMA32(cur[0], cur[5], a01);
    a10 = MFMA32(cur[3], cur[4], a10); a10 = MFMA32(cur[1], cur[6], a10); a10 = MFMA32(cur[1], cur[4], a10);
    a11 = MFMA32(cur[3], cur[5], a11); a11 = MFMA32(cur[1], cur[7], a11); a11 = MFMA32(cur[1], cur[5], a11);
#pragma unroll
    for (int i = 0; i < 8; ++i) { cur[i] = nxt[i]; nxt[i] = nx2[i]; }
  }

  // ---- epilogue via LDS tile (coalesced stores) ----
  const int n0 = bn * 32;
  const int which = n0 >> 9;
  const int h  = (n0 & 511) >> 6;
  const int d0 = n0 & 63;                 // 0 or 32
  const int b  = (bm >= 6) ? 1 : 0;
  const int bh = b * 8 + h;
  const int tt0 = (bm - b * 6) * 32;

  v4f accs[2][2] = {{a00, a01}, {a10, a11}};
#pragma unroll
  for (int mt = 0; mt < 2; ++mt)
#pragma unroll
    for (int nt = 0; nt < 2; ++nt) {
      const float bv = bin[n0 + nt * 16 + c];
#pragma unroll
      for (int r = 0; r < 4; ++r)
        tile[(mt * 16 + (q << 2) + r) * 33 + nt * 16 + c] = accs[mt][nt][r] + bv;
    }
  __syncthreads();

  const int rr = lane >> 1, cc0 = (lane & 1) * 16;
  if (which == 0 || which == 4) {
    float* out = wsf + (which == 4 ? 196608 : 0) + ((bh * 192 + tt0 + rr) << 6) + d0 + cc0;
    const float s = (which == 0) ? QSCALE : 1.0f;
#pragma unroll
    for (int i = 0; i < 16; i += 4) {
      v4f v;
#pragma unroll
      for (int j = 0; j < 4; ++j) v[j] = tile[rr * 33 + cc0 + i + j] * s;
      *(v4f*)(out + i) = v;
    }
  } else if (which == 1 || which == 3) {
    unsigned short* out = wshd + (which == 3 ? 196608 : 0) + ((bh * 192 + tt0 + rr) << 6) + d0 + cc0;
#pragma unroll
    for (int hf = 0; hf < 2; ++hf) {
      union { uint4 u; unsigned short us[8]; } pk;
#pragma unroll
      for (int j = 0; j < 8; ++j) pk.us[j] = f2bf(tile[rr * 33 + cc0 + hf * 8 + j]);
      *(uint4*)(out + hf * 8) = pk.u;
    }
  } else {  // which == 2: v1t, transposed + permuted (column reads from LDS)
    const int dd = rr, p0 = cc0;
    unsigned short* out = wshd + 393216 + ((bh << 6) + d0 + dd) * 192 + tt0 + p0;
#pragma unroll
    for (int hf = 0; hf < 2; ++hf) {
      union { uint4 u; unsigned short us[8]; } pk;
#pragma unroll
      for (int j = 0; j < 8; ++j) {
        const int p = p0 + hf * 8 + j;
        pk.us[j] = f2bf(tile[v1perm_inv(p) * 33 + dd]);
      }
      *(uint4*)(out + hf * 8) = pk.u;
    }
  }
}

// ------------------------------ Phase 2: attention -------------------------
// grid = 16(bh)*12(i)*4(ksplit) = 768 blocks, 256 thr (4 waves).
// Wave (jh = wv&1, kh = wv>>1): 6 jt x 24 ksteps. Registers: k1f[6][2] (48),
// vf[3][4] (48, kstep-invariant), q (16), acc (16), oS (4).
// Per kstep (batched stages): K2 f32 from LDS (broadcast, no cvt) -> af build
// (16 mul + 8 cvt_pk) -> 12 logits MFMA (swapped) -> 24 exp -> 12 cvt_pk ->
// 3 S-MFMA (ones A-frag) + 12 PV MFMA (swapped) -> 16 FMA v2-scale.
__global__ __launch_bounds__(256, 2) void attn_kernel(
    const float* __restrict__ wsf, const unsigned short* __restrict__ wsh,
    float* __restrict__ accp, float* __restrict__ Sp) {
  __shared__ char smem[17408];
  float* K2f = (float*)smem;              // [48][64] f32 (12288 B)

  const int tid  = threadIdx.x;
  const int wv   = tid >> 6;
  const int lane = tid & 63;
  const int c    = lane & 15;
  const int quad = lane >> 4;
  const int jh   = wv & 1;
  const int kh   = wv >> 1;

  const int bb = blockIdx.x;
  const int kb = bb & 3;
  const int it = (bb >> 2) % 12;
  const int bh = bb / 48;

  const unsigned short* k1g = wsh + bh * 192 * 64;
  const unsigned short* v1g = wsh + 393216 + bh * 64 * 192;
  const unsigned short* k2g = wsh + 196608 + bh * 192 * 64;
  const float*          v2g = wsf + 196608 + bh * 12288;   // [192][64] f32

  // stage this block's 48 k2 rows, EXPANDED to f32
  for (int idx = tid; idx < 384; idx += 256) {
    const int r = idx >> 3, c8 = (idx & 7) * 8;
    union { uint4 u4; unsigned short us[8]; } t;
    t.u4 = *(const uint4*)(k2g + (kb * 48 + r) * 64 + c8);
    v4f lo, hi;
#pragma unroll
    for (int e = 0; e < 4; ++e) { lo[e] = bf2f(t.us[e]); hi[e] = bf2f(t.us[4 + e]); }
    *(v4f*)(K2f + r * 64 + c8)     = lo;
    *(v4f*)(K2f + r * 64 + c8 + 4) = hi;
  }

  // K1 A-frags (this wave's 6 jt): frag[j][h] = K1[(jh*6+j)*16+c][h*32+quad*8..+8]
  v8s k1f[6][2];
#pragma unroll
  for (int j = 0; j < 6; ++j) {
    const unsigned short* kp = k1g + (((jh * 6 + j) * 16 + c) << 6) + (quad << 3);
    k1f[j][0] = *(const v8s*)(kp);
    k1f[j][1] = *(const v8s*)(kp + 32);
  }

  // PV A-frags (kstep-invariant): vf[m][dt] = V1t[d=dt*16+c][chunk(jh*3+m), pos quad*8..+8]
  v8s vf[3][4];
#pragma unroll
  for (int m = 0; m < 3; ++m)
#pragma unroll
    for (int dt = 0; dt < 4; ++dt)
      vf[m][dt] = *(const v8s*)(v1g + (dt * 16 + c) * 192 + ((jh * 3 + m) << 5) + (quad << 3));

  // q rows (fp32, pre-scaled): i = it*16+c, d = quad*8+e (+32)
  const float* qg = wsf + ((bh * 192 + it * 16 + c) << 6) + (quad << 3);
  float q0[8], q1[8];
  {
    v4f qa = *(const v4f*)(qg), qb = *(const v4f*)(qg + 4);
    v4f qc = *(const v4f*)(qg + 32), qd = *(const v4f*)(qg + 36);
#pragma unroll
    for (int e = 0; e < 4; ++e) {
      q0[e] = qa[e]; q0[4 + e] = qb[e];
      q1[e] = qc[e]; q1[4 + e] = qd[e];
    }
  }
  __syncthreads();   // K2f staged; no barriers until epilogue

  const v4f z = {0.f, 0.f, 0.f, 0.f};
  v4f acc[4] = {z, z, z, z};
  v4f oS = z;
  const short one = (short)0x3F80;
  const v8s ones = {one, one, one, one, one, one, one, one};

  union AF { v8s v; unsigned u[4]; };

#pragma unroll 1
  for (int ks = 0; ks < 24; ++ks) {
    const int rl = kh * 24 + ks;             // row in K2f / block-local k
    const float* kp = K2f + (rl << 6) + (quad << 3);
    const v4f k2a = *(const v4f*)(kp);       // d = quad*8+0..3
    const v4f k2b = *(const v4f*)(kp + 4);   // d = quad*8+4..7
    const v4f k2c = *(const v4f*)(kp + 32);  // half1
    const v4f k2d = *(const v4f*)(kp + 36);
    // v2: vt[dt][r] = v2[k][dt*16 + quad*4 + r]
    const float* vb = v2g + ((kb * 48 + rl) << 6) + (quad << 2);
    const v4f vt0 = *(const v4f*)(vb);
    const v4f vt1 = *(const v4f*)(vb + 16);
    const v4f vt2 = *(const v4f*)(vb + 32);
    const v4f vt3 = *(const v4f*)(vb + 48);

    AF af0, af1;  // B-frags of L-MFMA: (q*k2) for d-halves 0/1, col index = i = c
    af0.u[0] = pack_bf16(q0[0] * k2a[0], q0[1] * k2a[1]);
    af0.u[1] = pack_bf16(q0[2] * k2a[2], q0[3] * k2a[3]);
    af0.u[2] = pack_bf16(q0[4] * k2b[0], q0[5] * k2b[1]);
    af0.u[3] = pack_bf16(q0[6] * k2b[2], q0[7] * k2b[3]);
    af1.u[0] = pack_bf16(q1[0] * k2c[0], q1[1] * k2c[1]);
    af1.u[1] = pack_bf16(q1[2] * k2c[2], q1[3] * k2c[3]);
    af1.u[2] = pack_bf16(q1[4] * k2d[0], q1[5] * k2d[1]);
    af1.u[3] = pack_bf16(q1[6] * k2d[2], q1[7] * k2d[3]);

    // stage 1: all 12 logits MFMA (swapped: lane holds P[i=c][j=jt*16+quad*4+r])
    v4f C[6];
#pragma unroll
    for (int jj = 0; jj < 6; ++jj) {
      v4f t0 = MFMA32(k1f[jj][0], af0.v, z);
      C[jj] = MFMA32(k1f[jj][1], af1.v, t0);
    }
    // stage 2: 24 exp
#pragma unroll
    for (int jj = 0; jj < 6; ++jj)
#pragma unroll
      for (int r = 0; r < 4; ++r) C[jj][r] = EXP2F(C[jj][r]);
    // stage 3: pack into PV B-frags
    AF pp[3];
#pragma unroll
    for (int m = 0; m < 3; ++m) {
      pp[m].u[0] = pack_bf16(C[2*m][0],   C[2*m][1]);
      pp[m].u[1] = pack_bf16(C[2*m][2],   C[2*m][3]);
      pp[m].u[2] = pack_bf16(C[2*m+1][0], C[2*m+1][1]);
      pp[m].u[3] = pack_bf16(C[2*m+1][2], C[2*m+1][3]);
    }
    // stage 4: S-sum MFMA (ones A-frag; D[r][c]=S[i=c], rows identical)
#pragma unroll
    for (int m = 0; m < 3; ++m) oS = MFMA32(ones, pp[m].v, oS);
    // stage 5: PV MFMAs (swapped: out^T)
    v4f o0 = z, o1 = z, o2 = z, o3 = z;
#pragma unroll
    for (int m = 0; m < 3; ++m) {
      o0 = MFMA32(vf[m][0], pp[m].v, o0);
      o1 = MFMA32(vf[m][1], pp[m].v, o1);
      o2 = MFMA32(vf[m][2], pp[m].v, o2);
      o3 = MFMA32(vf[m][3], pp[m].v, o3);
    }
    acc[0] += o0 * vt0;
    acc[1] += o1 * vt1;
    acc[2] += o2 * vt2;
    acc[3] += o3 * vt3;
  }

  __syncthreads();  // reuse smem for cross-wave reduction
  float* redA = (float*)smem;              // [4][16 i][64 d]
  float* redS = (float*)smem + 4096;       // [4 wv][16 i]

  // lane (c,quad): acc[dt][r] -> i=c, d=dt*16+quad*4+r (v4f rows contiguous)
#pragma unroll
  for (int dt = 0; dt < 4; ++dt)
    *(v4f*)(redA + wv * 1024 + (c << 6) + (dt << 4) + (quad << 2)) = acc[dt];
  if (quad == 0) redS[wv * 16 + c] = oS[0];   // all rows/quads hold same S[c]
  __syncthreads();

  const int pbase = (bh * 12 + it) * 4 + kb;
  float* ap_out = accp + pbase * 1024;
  for (int idx = tid; idx < 1024; idx += 256)
    ap_out[idx] = redA[idx] + redA[1024 + idx] + redA[2048 + idx] + redA[3072 + idx];
  if (tid < 16)
    Sp[pbase * 16 + tid] = redS[tid] + redS[16 + tid] + redS[32 + tid] + redS[48 + tid];
}

// ------------------------------ Phase 2.5: normalize -----------------------
__global__ __launch_bounds__(256) void norm_kernel(
    const float* __restrict__ accp, const float* __restrict__ Sp,
    unsigned short* __restrict__ wsh) {
  const int flat = blockIdx.x * 2048 + threadIdx.x * 8;
  const int m = flat >> 9, cc = flat & 511;
  const int b = (m >= 192) ? 1 : 0;
  const int tt = m - (b ? 192 : 0);
  const int h = cc >> 6, d0 = cc & 63;
  const int bh = b * 8 + h, it = tt >> 4, i = tt & 15;
  const int pb = (bh * 12 + it) * 4;
  const float* ap = accp + pb * 1024 + (i << 6) + d0;
  v4f a0 = *(const v4f*)(ap), a1 = *(const v4f*)(ap + 4);
  float Sv = Sp[pb * 16 + i];
#pragma unroll
  for (int kb = 1; kb < 4; ++kb) {
    a0 += *(const v4f*)(ap + kb * 1024);
    a1 += *(const v4f*)(ap + kb * 1024 + 4);
    Sv += Sp[(pb + kb) * 16 + i];
  }
  const float inv = 1.0f / Sv;
  union { uint4 u; unsigned short us[8]; } ph, pl;
#pragma unroll
  for (int j = 0; j < 4; ++j) {
    float v = a0[j] * inv;
    unsigned short hh = f2bf(v);
    ph.us[j] = hh; pl.us[j] = f2bf(v - bf2f(hh));
    v = a1[j] * inv;
    hh = f2bf(v);
    ph.us[4 + j] = hh; pl.us[4 + j] = f2bf(v - bf2f(hh));
  }
  *(uint4*)(wsh + OH_OFF + flat) = ph.u;
  *(uint4*)(wsh + OL_OFF + flat) = pl.u;
}

// ------------------------------ Phase 3: out GEMM (bf16x3 MFMA) ------------
// grid 192 x 64thr: M=384 (12), N=512 (16), K=512, prefetch depth 2.
__global__ __launch_bounds__(64) void outp_kernel(
    const unsigned short* __restrict__ wsh, const float* __restrict__ bout,
    float* __restrict__ y) {
  const int lane = threadIdx.x;
  const int c = lane & 15, q = lane >> 4;
  const int bm = blockIdx.x % 12, bn = blockIdx.x / 12;

  const unsigned short* base[8];
  base[0] = wsh + OH_OFF + (bm * 32 + c) * 512 + (q << 3);
  base[1] = base[0] + 16 * 512;
  base[2] = wsh + OL_OFF + (bm * 32 + c) * 512 + (q << 3);
  base[3] = base[2] + 16 * 512;
  base[4] = wsh + WOTH_OFF + (bn * 32 + c) * 512 + (q << 3);
  base[5] = base[4] + 16 * 512;
  base[6] = wsh + WOTL_OFF + (bn * 32 + c) * 512 + (q << 3);
  base[7] = base[6] + 16 * 512;

  const v4f z = {0.f, 0.f, 0.f, 0.f};
  v4f a00 = z, a01 = z, a10 = z, a11 = z;

  v8s cur[8], nxt[8];
#pragma unroll
  for (int i = 0; i < 8; ++i) cur[i] = *(const v8s*)(base[i]);
#pragma unroll
  for (int i = 0; i < 8; ++i) nxt[i] = *(const v8s*)(base[i] + 32);

#pragma unroll 1
  for (int ks = 0; ks < 16; ++ks) {
    v8s nx2[8];
    if (ks < 14) {
      const int o = (ks + 2) * 32;
#pragma unroll
      for (int i = 0; i < 8; ++i) nx2[i] = *(const v8s*)(base[i] + o);
    }
    a00 = MFMA32(cur[2], cur[4], a00); a00 = MFMA32(cur[0], cur[6], a00); a00 = MFMA32(cur[0], cur[4], a00);
    a01 = MFMA32(cur[2], cur[5], a01); a01 = MFMA32(cur[0], cur[7], a01); a01 = MFMA32(cur[0], cur[5], a01);
    a10 = MFMA32(cur[3], cur[4], a10); a10 = MFMA32(cur[1], cur[6], a10); a10 = MFMA32(cur[1], cur[4], a10);
    a11 = MFMA32(cur[3], cur[5], a11); a11 = MFMA32(cur[1], cur[7], a11); a11 = MFMA32(cur[1], cur[5], a11);
#pragma unroll
    for (int i = 0; i < 8; ++i) { cur[i] = nxt[i]; nxt[i] = nx2[i]; }
  }

  v4f accs[2][2] = {{a00, a01}, {a10, a11}};
#pragma unroll
  for (int mt = 0; mt < 2; ++mt) {
#pragma unroll
    for (int nt = 0; nt < 2; ++nt) {
      const int n = bn * 32 + nt * 16 + c;
      const float bv = bout[n];
#pragma unroll
      for (int r = 0; r < 4; ++r) {
        const int m = bm * 32 + mt * 16 + (q << 2) + r;
        y[m * 512 + n] = accs[mt][nt][r] + bv;
      }
    }
  }
}

// ------------------------------ launcher -----------------------------------
extern "C" void kernel_launch(void* const* d_in, const int* in_sizes, int n_in,
                              void* d_out, int out_size, void* d_ws, size_t ws_size,
                              hipStream_t stream) {
  const float* x    = (const float*)d_in[0];
  const float* Win  = (const float*)d_in[1];
  const float* bin  = (const float*)d_in[2];
  const float* Wout = (const float*)d_in[3];
  const float* bout = (const float*)d_in[4];

  float* wsf = (float*)d_ws;
  unsigned short* wsh = (unsigned short*)(wsf + 1191936);
  float* accp = wsf + 393216;
  float* Sp   = wsf + 1179648;

  prep_kernel<<<dim3(864), 256, 0, stream>>>(x, Win, Wout, wsh);
  proj_kernel<<<dim3(960), 64, 0, stream>>>(wsh, bin, wsf, wsh);
  attn_kernel<<<dim3(768), 256, 0, stream>>>(wsf, wsh, accp, Sp);
  norm_kernel<<<dim3(96), 256, 0, stream>>>(accp, Sp, wsh);
  outp_kernel<<<dim3(192), 64, 0, stream>>>(wsh, bout, (float*)d_out);
}